// Round 2
// baseline (90.790 us; speedup 1.0000x reference)
//
#include <hip/hip_runtime.h>

#define BATCH 8
#define ROWS  2048
#define WIDTH 4096
#define COLS  4096
#define KB    1024   // WIDTH / 4 (gating blocks along k)
#define CB    1024   // COLS  / 4 (gating blocks along c)
#define RCH   64     // rows per colsum block

// ---------------------------------------------------------------------------
// Fused kernel, 2048 blocks. Two independent jobs share the HBM pipe:
//   even blockIdx (1024 blocks): xs[b,k] = sum_r X[b,r,k]   (268 MB of X)
//   odd  blockIdx (1024 blocks): wg[b,k] = sum_c W[k,c]*G[b,k/4,c/4]
//                                 (67 MB of W + 33.5 MB of G), one block per kb
// ---------------------------------------------------------------------------
__global__ __launch_bounds__(256) void fused_kernel(const float4* __restrict__ Xv,
                                                    const float4* __restrict__ Wv,
                                                    const float* __restrict__ G,
                                                    float* __restrict__ xs,
                                                    float* __restrict__ wg) {
    const int tid = threadIdx.x;
    if (blockIdx.x & 1) {
        // ---------------- gate-contraction: one block per kb ----------------
        const int kb = blockIdx.x >> 1;  // [0, 1024)
        float acc[8][4];
#pragma unroll
        for (int b = 0; b < 8; ++b)
#pragma unroll
            for (int j = 0; j < 4; ++j) acc[b][j] = 0.f;

#pragma unroll
        for (int chunk = 0; chunk < CB / 256; ++chunk) {
            const int cb = chunk * 256 + tid;
            float w4[4];
#pragma unroll
            for (int j = 0; j < 4; ++j) {
                float4 w = Wv[(size_t)(4 * kb + j) * CB + cb];  // W[4kb+j, 4cb..4cb+3]
                w4[j] = (w.x + w.y) + (w.z + w.w);
            }
#pragma unroll
            for (int b = 0; b < 8; ++b) {
                float g = G[((size_t)b * KB + kb) * CB + cb];
#pragma unroll
                for (int j = 0; j < 4; ++j) acc[b][j] += g * w4[j];
            }
        }

        // reduce 32 accumulators (b,j) across 256 threads: wave butterfly + LDS
        __shared__ float lds[4][32];
        const int lane = tid & 63, wid = tid >> 6;
#pragma unroll
        for (int v = 0; v < 32; ++v) {
            float x = acc[v >> 2][v & 3];
#pragma unroll
            for (int o = 1; o < 64; o <<= 1) x += __shfl_xor(x, o, 64);
            if (lane == 0) lds[wid][v] = x;
        }
        __syncthreads();
        if (tid < 32) {
            float r = lds[0][tid] + lds[1][tid] + lds[2][tid] + lds[3][tid];
            const int b = tid >> 2, j = tid & 3;
            wg[(size_t)b * WIDTH + 4 * kb + j] = r;  // deterministic direct store
        }
    } else {
        // ---------------- colsum of X (atomics into zeroed xs) --------------
        const int c  = blockIdx.x >> 1;          // [0, 1024)
        const int k4 = (c & 3) * 256 + tid;      // k/4 in [0, 1024)
        const int b  = (c >> 2) & 7;
        const int r0 = (c >> 5) * RCH;

        const float4* p = Xv + (size_t)(b * ROWS + r0) * (WIDTH / 4) + k4;
        float ax = 0.f, ay = 0.f, az = 0.f, aw = 0.f;
#pragma unroll 8
        for (int r = 0; r < RCH; ++r) {
            float4 v = p[(size_t)r * (WIDTH / 4)];
            ax += v.x; ay += v.y; az += v.z; aw += v.w;
        }
        float* dst = xs + (size_t)b * WIDTH + 4 * k4;
        atomicAdd(dst + 0, ax);
        atomicAdd(dst + 1, ay);
        atomicAdd(dst + 2, az);
        atomicAdd(dst + 3, aw);
    }
}

// ---------------------------------------------------------------------------
// Final: s = sum_{b,k} xs[b,k]*wg[b,k]; out = s*s.  One block over 2x128 KB.
// ---------------------------------------------------------------------------
__global__ __launch_bounds__(256) void final_kernel(const float4* __restrict__ xs4,
                                                    const float4* __restrict__ wg4,
                                                    float* __restrict__ out) {
    float acc = 0.f;
    for (int i = threadIdx.x; i < BATCH * WIDTH / 4; i += 256) {
        float4 a = xs4[i], b = wg4[i];
        acc += a.x * b.x + a.y * b.y + a.z * b.z + a.w * b.w;
    }
    __shared__ float red[256];
    red[threadIdx.x] = acc;
    __syncthreads();
    for (int o = 128; o > 0; o >>= 1) {
        if (threadIdx.x < o) red[threadIdx.x] += red[threadIdx.x + o];
        __syncthreads();
    }
    if (threadIdx.x == 0) {
        float s = red[0];
        out[0] = s * s;
    }
}

extern "C" void kernel_launch(void* const* d_in, const int* in_sizes, int n_in,
                              void* d_out, int out_size, void* d_ws, size_t ws_size,
                              hipStream_t stream) {
    const float* X = (const float*)d_in[0];  // (8, 2048, 4096)
    const float* W = (const float*)d_in[1];  // (4096, 4096)
    const float* G = (const float*)d_in[2];  // (8, 1024, 1024)
    float* out = (float*)d_out;              // scalar

    float* xs = (float*)d_ws;                // 8*4096 floats (atomic targets)
    float* wg = xs + BATCH * WIDTH;          // 8*4096 floats (direct stores)

    // zero only the atomic accumulator region — wg is fully overwritten
    hipMemsetAsync(xs, 0, (size_t)BATCH * WIDTH * sizeof(float), stream);

    fused_kernel<<<2048, 256, 0, stream>>>((const float4*)X, (const float4*)W, G, xs, wg);

    final_kernel<<<1, 256, 0, stream>>>((const float4*)xs, (const float4*)wg, out);
}